// Round 15
// baseline (215.780 us; speedup 1.0000x reference)
//
#include <hip/hip_runtime.h>

#define N_NODES 50000
#define N_EDGES 800000
#define IN_FEATS 256
#define HIDDEN 128
#define OUT_FEATS 64

// R26: R25 (214.4us) + deep load-batching in both gathers. R25 counters:
// gather_gemm2 43us, VGPR=28 (compiler issues 2 loads/iter, no
// pipelining), beyond-L2 traffic at 8-XCD floor but only 2.6 TB/s ->
// concurrency-limited. Fix: wave-uniform fast path for d64<=32 (Poisson16,
// P=99.98%): all 8 (gg2) / 4 (g2) row-loads issued back-to-back from
// shuffle-derived addresses, then one fma chain in original edge order
// (bit-identical). Masked edges: weight 0, row 0 (L1-hot). deg>32 falls
// back to R25 loop.
#define NCHUNK 64            // edge chunks (= privatized copies)
#define EPC 12500            // edges per chunk
#define NBH 16384            // hist bins per range (u8)
#define NRH 4                // ceil(50000/16384)
#define NBTH (NRH * NBH)     // 65536 padded bins per copy (u8 each)
#define HBLKH (NRH * NCHUNK) // 256 hist blocks
#define NBF 8192             // fill bins per range (int cur, 32 KB)
#define NRF 7                // ceil(50000/8192)
#define FBLK (NRF * NCHUNK)  // 448 fill blocks
#define ROWBLK ((N_NODES + 63) / 64)  // 782 gemm blocks

typedef _Float16 f16;
typedef _Float16 f16x8 __attribute__((ext_vector_type(8)));
typedef float f32x4 __attribute__((ext_vector_type(4)));

// ------------------------------------------------------------ W transpose
// W1T[n][k] = W1[k][n] (128x256 f16); W2T[n][k] = W2[k][n] (64x128 f16).
__global__ __launch_bounds__(256) void wtrans(const float* __restrict__ W1,
                                              const float* __restrict__ W2,
                                              f16* __restrict__ W1T,
                                              f16* __restrict__ W2T) {
  int i = blockIdx.x * 256 + threadIdx.x;
  if (i < 128 * 256) {
    int n = i >> 8, k = i & 255;
    W1T[i] = (f16)W1[k * 128 + n];
  } else {
    int j = i - 128 * 256;
    int n = j >> 7, k = j & 127;
    W2T[j] = (f16)W2[k * 64 + n];
  }
}

// ------------------------------------------- fused hist + gemm1 kernel
// Blocks [0,256): u8 LDS histogram of src/dst (zero global atomics).
// Blocks [256,1038): gemm1 m1 = f16(X)@W1 — 64-row x 128-col tile, x
// row-frags in VGPRs (read once), two 64-col halves via one 32 KB
// XOR-swizzled LDS B-tile staged from W1T by f16x8 copy (8 iters/half).
// m1 UNSCALED — norm_src applied per-edge in gather by linearity.
__global__ __launch_bounds__(256) void hist_gemm_kernel(
    const int* __restrict__ src, const int* __restrict__ dst,
    unsigned* __restrict__ hist_src, unsigned* __restrict__ hist_dst,
    const f16* __restrict__ W1T, const float* __restrict__ x,
    f16* __restrict__ m1) {
  // union: u8 hist counters (2 x 16 KB) / gemm B-tile 64x256 f16 swizzled
  __shared__ __align__(16) unsigned smem[8192];  // 32768 B exactly
  if (blockIdx.x < HBLKH) {
    unsigned* ls = smem;             // u8[NBH] packed, src bins
    unsigned* ld2 = smem + NBH / 4;  // u8[NBH] packed, dst bins
    const int r = blockIdx.x % NRH;
    const int c = blockIdx.x / NRH;
    const int lo = r * NBH;
    for (int i = threadIdx.x; i < NBH / 4; i += 256) {
      ls[i] = 0;
      ld2[i] = 0;
    }
    __syncthreads();
    const int4* s4 = (const int4*)(src + c * EPC);
    const int4* d4 = (const int4*)(dst + c * EPC);
    for (int i = threadIdx.x; i < EPC / 4; i += 256) {
      int4 s = s4[i];
      int4 d = d4[i];
      unsigned b;
      b = (unsigned)(s.x - lo); if (b < NBH) atomicAdd(&ls[b >> 2], 1u << ((b & 3) << 3));
      b = (unsigned)(s.y - lo); if (b < NBH) atomicAdd(&ls[b >> 2], 1u << ((b & 3) << 3));
      b = (unsigned)(s.z - lo); if (b < NBH) atomicAdd(&ls[b >> 2], 1u << ((b & 3) << 3));
      b = (unsigned)(s.w - lo); if (b < NBH) atomicAdd(&ls[b >> 2], 1u << ((b & 3) << 3));
      b = (unsigned)(d.x - lo); if (b < NBH) atomicAdd(&ld2[b >> 2], 1u << ((b & 3) << 3));
      b = (unsigned)(d.y - lo); if (b < NBH) atomicAdd(&ld2[b >> 2], 1u << ((b & 3) << 3));
      b = (unsigned)(d.z - lo); if (b < NBH) atomicAdd(&ld2[b >> 2], 1u << ((b & 3) << 3));
      b = (unsigned)(d.w - lo); if (b < NBH) atomicAdd(&ld2[b >> 2], 1u << ((b & 3) << 3));
    }
    __syncthreads();
    unsigned* hs = hist_src + ((long)c * NBTH + lo) / 4;
    unsigned* hd = hist_dst + ((long)c * NBTH + lo) / 4;
    for (int i = threadIdx.x; i < NBH / 4; i += 256) {
      hs[i] = ls[i];
      hd[i] = ld2[i];
    }
  } else {
    // ------- gemm1: two 64-col halves, one 32 KB swizzled Bs.
    // Swizzle (both sides, same involution): byte ^= (n&7)<<4, n = out col.
    char* BsBytes = (char*)smem;
    const int rb = blockIdx.x - HBLKH;
    const int wave = threadIdx.x >> 6;
    const int lane = threadIdx.x & 63;
    const int m = lane & 15;
    const int q = lane >> 4;
    const int row0 = rb * 64 + wave * 16;
    const int ra = min(row0 + m, N_NODES - 1);

    // load + convert this lane's x row fragments ONCE (8 x f16x8 = 32 VGPR)
    f16x8 a[8];
#pragma unroll
    for (int ki = 0; ki < 8; ++ki) {
      const float* p = x + (long)ra * IN_FEATS + ki * 32 + q * 8;
      float4 u0 = *(const float4*)p;
      float4 u1 = *(const float4*)(p + 4);
      a[ki][0] = (f16)u0.x; a[ki][1] = (f16)u0.y;
      a[ki][2] = (f16)u0.z; a[ki][3] = (f16)u0.w;
      a[ki][4] = (f16)u1.x; a[ki][5] = (f16)u1.y;
      a[ki][6] = (f16)u1.z; a[ki][7] = (f16)u1.w;
    }

    for (int h = 0; h < 2; ++h) {
      const int col0 = h * 64;
      // stage Bs[n][0..255] = W1T[col0+n][0..255] as 16-B chunks; global
      // side fully coalesced, swizzled 16-B LDS writes bank-uniform.
#pragma unroll
      for (int idx = threadIdx.x; idx < 64 * 32; idx += 256) {
        int n = idx >> 5;
        int kq = idx & 31;
        f16x8 v = *(const f16x8*)(W1T + (col0 + n) * IN_FEATS + kq * 8);
        unsigned bo = (unsigned)(n * 512 + kq * 16);
        bo ^= (unsigned)((n & 7) << 4);
        *(f16x8*)(BsBytes + bo) = v;
      }
      __syncthreads();

      f32x4 acc[4];
#pragma unroll
      for (int t = 0; t < 4; ++t) acc[t] = (f32x4){0.f, 0.f, 0.f, 0.f};

#pragma unroll
      for (int ki = 0; ki < 8; ++ki) {
        const int kb2 = (ki * 32 + q * 8) * 2;  // byte offset in row
#pragma unroll
        for (int t = 0; t < 4; ++t) {
          int nrow = t * 16 + m;
          unsigned bo = (unsigned)(nrow * 512 + kb2);
          bo ^= (unsigned)((nrow & 7) << 4);
          f16x8 bfr = *(const f16x8*)(BsBytes + bo);
          acc[t] = __builtin_amdgcn_mfma_f32_16x16x32_f16(a[ki], bfr, acc[t], 0, 0, 0);
        }
      }
      __syncthreads();  // all reads of Bs done before next half's restage

#pragma unroll
      for (int rr = 0; rr < 4; ++rr) {
        int row = row0 + q * 4 + rr;
        if (row < N_NODES) {
#pragma unroll
          for (int t = 0; t < 4; ++t)
            m1[(long)row * HIDDEN + col0 + t * 16 + m] = (f16)acc[t][rr];
        }
      }
    }
  }
}

// sum copies -> norms; hist_dst -> exclusive prefix over copies (u8; max
// in-degree ~50 << 256); emits per-block degree sums (folded scan1).
__global__ __launch_bounds__(256) void reduce_kernel(
    const unsigned* __restrict__ hist_src, unsigned* __restrict__ hist_dst,
    int* __restrict__ deg_in, float* __restrict__ norm_src,
    float* __restrict__ norm_dst, int* __restrict__ partial) {
  const unsigned char* hs = (const unsigned char*)hist_src;
  unsigned char* hd = (unsigned char*)hist_dst;
  int n = blockIdx.x * 256 + threadIdx.x;
  int run = 0;
  if (n < N_NODES) {
    int so = 0;
#pragma unroll 8
    for (int c = 0; c < NCHUNK; ++c) so += hs[(long)c * NBTH + n];
    norm_src[n] = rsqrtf((float)max(so, 1));
#pragma unroll 8
    for (int c = 0; c < NCHUNK; ++c) {
      int t = hd[(long)c * NBTH + n];
      hd[(long)c * NBTH + n] = (unsigned char)run;
      run += t;
    }
    deg_in[n] = run;
    norm_dst[n] = rsqrtf((float)max(run, 1));
  }
  __shared__ int sd[256];
  sd[threadIdx.x] = run;
  __syncthreads();
  for (int s = 128; s > 0; s >>= 1) {
    if (threadIdx.x < s) sd[threadIdx.x] += sd[threadIdx.x + s];
    __syncthreads();
  }
  if (threadIdx.x == 0) partial[blockIdx.x] = sd[0];
}

// ------------------------------------------------- scan (scan2 folded in)
__global__ __launch_bounds__(256) void scan3(const int* __restrict__ deg,
                                             const int* __restrict__ partial,
                                             int* __restrict__ rowptr) {
  __shared__ int sd[256];
  __shared__ int sp[256];
  const int w = blockIdx.x;
  int pv = (threadIdx.x < 196) ? partial[threadIdx.x] : 0;
  sp[threadIdx.x] = pv;
  __syncthreads();
  for (int off = 1; off < 256; off <<= 1) {
    int t = sp[threadIdx.x] +
            ((threadIdx.x >= off) ? sp[threadIdx.x - off] : 0);
    __syncthreads();
    sp[threadIdx.x] = t;
    __syncthreads();
  }
  const int base = (w == 0) ? 0 : sp[w - 1];
  int i = w * 256 + threadIdx.x;
  int v = (i < N_NODES) ? deg[i] : 0;
  sd[threadIdx.x] = v;
  __syncthreads();
  for (int off = 1; off < 256; off <<= 1) {
    int t = sd[threadIdx.x] +
            ((threadIdx.x >= off) ? sd[threadIdx.x - off] : 0);
    __syncthreads();
    sd[threadIdx.x] = t;
    __syncthreads();
  }
  if (i < N_NODES) rowptr[i] = base + sd[threadIdx.x] - v;
  if (w == 0 && threadIdx.x == 0) rowptr[N_NODES] = N_EDGES;
}

// ------------------------------------------------------------- CSR fill
__global__ __launch_bounds__(256) void fill_csr(
    const int* __restrict__ src, const int* __restrict__ dst,
    const int* __restrict__ rowptr, const unsigned* __restrict__ pref32,
    int* __restrict__ col) {
  __shared__ int cur[NBF];  // 32 KB
  const unsigned char* pref = (const unsigned char*)pref32;
  const int r = blockIdx.x % NRF;
  const int c = blockIdx.x / NRF;
  const int lo = r * NBF;
  for (int i = threadIdx.x; i < NBF; i += 256) {
    int n = lo + i;
    cur[i] = (n < N_NODES) ? rowptr[n] + pref[(long)c * NBTH + n] : 0;
  }
  __syncthreads();
  const int4* s4 = (const int4*)(src + c * EPC);
  const int4* d4 = (const int4*)(dst + c * EPC);
  for (int i = threadIdx.x; i < EPC / 4; i += 256) {
    int4 s = s4[i];
    int4 d = d4[i];
    unsigned b;
    b = (unsigned)(d.x - lo);
    if (b < NBF) col[atomicAdd(&cur[b], 1)] = s.x;
    b = (unsigned)(d.y - lo);
    if (b < NBF) col[atomicAdd(&cur[b], 1)] = s.y;
    b = (unsigned)(d.z - lo);
    if (b < NBF) col[atomicAdd(&cur[b], 1)] = s.z;
    b = (unsigned)(d.w - lo);
    if (b < NBF) col[atomicAdd(&cur[b], 1)] = s.w;
  }
}

// ------------------------------------- fused gather1 + gemm2 (layer 1+2a)
// Block = 16 dst nodes (4 waves x 4 sequential). Uniform-shuffle preload
// (R25-proven). R26: wave-uniform fast path d64<=32 — all 8 row-loads
// issued back-to-back (static v[8]), then one fma chain in original edge
// order (bit-identical). Masked edges: w=0, row 0 (L1-hot). deg>32 ->
// R25 loop + residual. Rows parked in padded LDS; one sync; each wave
// does one 16x16 tile of rows@W2T (4 MFMAs) to m2. 50000 = 3125*16.
__global__ __launch_bounds__(256) void gather_gemm2_kernel(
    const f16* __restrict__ M, const int* __restrict__ rowptr,
    const int* __restrict__ col, const float* __restrict__ nd,
    const float* __restrict__ ns, const float* __restrict__ b,
    const f16* __restrict__ W2T, f16* __restrict__ m2) {
  constexpr int LPR = 16;       // 128 f16 = 256 B row / 16 B per lane
  constexpr int EPW = 64 / LPR; // 4 edges in parallel
  constexpr int RS = 136;       // LDS row stride (f16): 272 B, 16-B aligned
  __shared__ __align__(16) f16 rows[16 * RS];  // 4352 B
  const int wave = threadIdx.x >> 6;
  const int lane = threadIdx.x & 63;
  const int eg = lane / LPR;
  const int t = lane % LPR;
  const int base = blockIdx.x * 16;

  for (int s = 0; s < 4; ++s) {
    const int n = base + wave * 4 + s;
    const int beg = rowptr[n];
    const int end = rowptr[n + 1];
    const int d64 = min(end - beg, 64);  // wave-uniform

    // batch preload: lane l holds col/ns of edge beg+l (masked -> 0)
    int e = beg + lane;
    int cidx = (e < end) ? col[e] : 0;
    float cns = (e < end) ? ns[cidx] : 0.f;

    float acc[8];
#pragma unroll
    for (int j = 0; j < 8; ++j) acc[j] = 0.f;

    if (d64 <= 32) {
      // fast path (P ~ 99.98%): group eg covers edges k*EPW+eg, k=0..7.
      // All shuffles uniform (all lanes active); all loads issued
      // back-to-back; fma chain follows original edge order.
      int sIdx[8];
      float w[8];
#pragma unroll
      for (int k = 0; k < 8; ++k) {
        int r = k * EPW + eg;  // < 32+4 <= 35 < 64
        sIdx[k] = __shfl(cidx, r, 64);
        w[k] = __shfl(cns, r, 64);
      }
      f16x8 v[8];
#pragma unroll
      for (int k = 0; k < 8; ++k)
        v[k] = *(const f16x8*)(M + (long)sIdx[k] * HIDDEN + t * 8);
#pragma unroll
      for (int k = 0; k < 8; ++k)
#pragma unroll
        for (int j = 0; j < 8; ++j) acc[j] += w[k] * (float)v[k][j];
    } else {
      // general path (rare): R25 uniform loop
      for (int rb2 = 0; rb2 < d64; rb2 += 2 * EPW) {
        int r0 = rb2 + eg;
        int r1 = rb2 + eg + EPW;
        int s0 = __shfl(cidx, r0, 64);
        float n0 = __shfl(cns, r0, 64);
        int s1 = __shfl(cidx, r1, 64);
        float n1 = __shfl(cns, r1, 64);
        f16x8 v0 = *(const f16x8*)(M + (long)s0 * HIDDEN + t * 8);
        f16x8 v1 = *(const f16x8*)(M + (long)s1 * HIDDEN + t * 8);
#pragma unroll
        for (int j = 0; j < 8; ++j)
          acc[j] += n0 * (float)v0[j] + n1 * (float)v1[j];
      }
      // residual comb (deg > 64; essentially never taken, exact fallback)
      for (int i2 = beg + 64 + eg; i2 < end; i2 += EPW) {
        int s0 = col[i2];
        float n0 = ns[s0];
        f16x8 v0 = *(const f16x8*)(M + (long)s0 * HIDDEN + t * 8);
#pragma unroll
        for (int j = 0; j < 8; ++j) acc[j] += n0 * (float)v0[j];
      }
    }

#pragma unroll
    for (int mm = LPR; mm < 64; mm <<= 1)
#pragma unroll
      for (int j = 0; j < 8; ++j) acc[j] += __shfl_xor(acc[j], mm, 64);

    if (eg == 0) {
      float sc = nd[n];
      float sn = ns[n];
      float4 bb0 = *(const float4*)(b + t * 8);
      float4 bb1 = *(const float4*)(b + t * 8 + 4);
      f16x8 o;
      o[0] = (f16)(fmaxf(acc[0] * sc + bb0.x, 0.f) * sn);
      o[1] = (f16)(fmaxf(acc[1] * sc + bb0.y, 0.f) * sn);
      o[2] = (f16)(fmaxf(acc[2] * sc + bb0.z, 0.f) * sn);
      o[3] = (f16)(fmaxf(acc[3] * sc + bb0.w, 0.f) * sn);
      o[4] = (f16)(fmaxf(acc[4] * sc + bb1.x, 0.f) * sn);
      o[5] = (f16)(fmaxf(acc[5] * sc + bb1.y, 0.f) * sn);
      o[6] = (f16)(fmaxf(acc[6] * sc + bb1.z, 0.f) * sn);
      o[7] = (f16)(fmaxf(acc[7] * sc + bb1.w, 0.f) * sn);
      *(f16x8*)(rows + (wave * 4 + s) * RS + t * 8) = o;
    }
  }
  __syncthreads();

  // GEMM tail: wave computes output cols [wave*16, wave*16+16) for the
  // block's 16 rows. K = HIDDEN = 128 -> 4 MFMA steps.
  const int m = lane & 15;
  const int q = lane >> 4;
  f32x4 acc2 = (f32x4){0.f, 0.f, 0.f, 0.f};
#pragma unroll
  for (int ki = 0; ki < 4; ++ki) {
    f16x8 a = *(const f16x8*)(rows + m * RS + ki * 32 + q * 8);
    f16x8 bf =
        *(const f16x8*)(W2T + (wave * 16 + m) * HIDDEN + ki * 32 + q * 8);
    acc2 = __builtin_amdgcn_mfma_f32_16x16x32_f16(a, bf, acc2, 0, 0, 0);
  }
#pragma unroll
  for (int r = 0; r < 4; ++r) {
    int row = base + q * 4 + r;
    m2[(long)row * OUT_FEATS + wave * 16 + m] = (f16)acc2[r];
  }
}

// ------------------------------------------------------------- gather2
// Uniform-shuffle scheme (LPR=8, EPW=8) + R26 fast path d64<=32 (4 loads
// back-to-back). w in {0,1} zeroes out-of-range edges exactly.
__global__ __launch_bounds__(256) void gather2_kernel(
    const f16* __restrict__ M, const int* __restrict__ rowptr,
    const int* __restrict__ col, const float* __restrict__ nd,
    const float* __restrict__ b, float* __restrict__ out) {
  constexpr int LPR = 8;        // 64 f16 = 128 B row / 16 B per lane
  constexpr int EPW = 64 / LPR; // 8 edges in parallel
  const int wave = threadIdx.x >> 6;
  const int lane = threadIdx.x & 63;
  const int eg = lane / LPR;
  const int t = lane % LPR;
  const int n = blockIdx.x * 4 + wave;
  if (n >= N_NODES) return;
  const int beg = rowptr[n];
  const int end = rowptr[n + 1];
  const int d64 = min(end - beg, 64);  // wave-uniform

  // batch preload: lane l holds col/weight of edge beg+l (masked -> 0)
  int e = beg + lane;
  int cidx = (e < end) ? col[e] : 0;
  float cw = (e < end) ? 1.f : 0.f;

  float acc[8];
#pragma unroll
  for (int j = 0; j < 8; ++j) acc[j] = 0.f;

  if (d64 <= 32) {
    // fast path: group eg covers edges k*EPW+eg, k=0..3.
    int sIdx[4];
    float w[4];
#pragma unroll
    for (int k = 0; k < 4; ++k) {
      int r = k * EPW + eg;  // < 24+8 = 32 < 64
      sIdx[k] = __shfl(cidx, r, 64);
      w[k] = __shfl(cw, r, 64);
    }
    f16x8 v[4];
#pragma unroll
    for (int k = 0; k < 4; ++k)
      v[k] = *(const f16x8*)(M + (long)sIdx[k] * OUT_FEATS + t * 8);
#pragma unroll
    for (int k = 0; k < 4; ++k)
#pragma unroll
      for (int j = 0; j < 8; ++j) acc[j] += w[k] * (float)v[k][j];
  } else {
    for (int rb2 = 0; rb2 < d64; rb2 += 2 * EPW) {
      int r0 = rb2 + eg;
      int r1 = rb2 + eg + EPW;
      int s0 = __shfl(cidx, r0, 64);
      float w0 = __shfl(cw, r0, 64);
      int s1 = __shfl(cidx, r1, 64);
      float w1 = __shfl(cw, r1, 64);
      f16x8 v0 = *(const f16x8*)(M + (long)s0 * OUT_FEATS + t * 8);
      f16x8 v1 = *(const f16x8*)(M + (long)s1 * OUT_FEATS + t * 8);
#pragma unroll
      for (int j = 0; j < 8; ++j)
        acc[j] += w0 * (float)v0[j] + w1 * (float)v1[j];
    }
    // residual comb (deg > 64; essentially never taken, exact fallback)
    for (int i2 = beg + 64 + eg; i2 < end; i2 += EPW) {
      int s0 = col[i2];
      f16x8 v0 = *(const f16x8*)(M + (long)s0 * OUT_FEATS + t * 8);
#pragma unroll
      for (int j = 0; j < 8; ++j) acc[j] += (float)v0[j];
    }
  }

#pragma unroll
  for (int m2v = LPR; m2v < 64; m2v <<= 1)
#pragma unroll
    for (int j = 0; j < 8; ++j) acc[j] += __shfl_xor(acc[j], m2v, 64);

  if (eg == 0) {
    float s = nd[n];
    float4 bb0 = *(const float4*)(b + t * 8);
    float4 bb1 = *(const float4*)(b + t * 8 + 4);
    float4 o0, o1;
    o0.x = acc[0] * s + bb0.x;
    o0.y = acc[1] * s + bb0.y;
    o0.z = acc[2] * s + bb0.z;
    o0.w = acc[3] * s + bb0.w;
    o1.x = acc[4] * s + bb1.x;
    o1.y = acc[5] * s + bb1.y;
    o1.z = acc[6] * s + bb1.z;
    o1.w = acc[7] * s + bb1.w;
    *(float4*)(out + (long)n * OUT_FEATS + t * 8) = o0;
    *(float4*)(out + (long)n * OUT_FEATS + t * 8 + 4) = o1;
  }
}

extern "C" void kernel_launch(void* const* d_in, const int* in_sizes, int n_in,
                              void* d_out, int out_size, void* d_ws,
                              size_t ws_size, hipStream_t stream) {
  const float* x = (const float*)d_in[0];
  const int* src = (const int*)d_in[1];
  const int* dst = (const int*)d_in[2];
  const float* W1 = (const float*)d_in[3];
  const float* b1 = (const float*)d_in[4];
  const float* W2 = (const float*)d_in[5];
  const float* b2 = (const float*)d_in[6];
  float* out = (float*)d_out;

  // ---- workspace layout
  int* wi = (int*)d_ws;
  int* partial = wi;            // [256]
  int* rowptr = wi + 256;       // [50001] (pad to 50004)
  int* deg_in = wi + 50260;     // [50000]
  int* col = wi + 100260;       // [800000] -> ends at int 900260
  float* wf = (float*)d_ws + 900260;
  float* norm_src = wf;         // [50000]
  float* norm_dst = wf + 50000; // [50000]
  f16* fh = (f16*)(wf + 100000);
  f16* W1T = fh;                          // [128*256]
  f16* W2T = fh + 128 * 256;              // [64*128]
  f16* m1 = W2T + 64 * 128;               // [50048*128]
  f16* histbuf = m1 + (long)50048 * 128;  // [50048*128] (hist tables only)
  f16* m2 = histbuf + (long)50048 * 128;  // [50048*64]

  // hist overlay on histbuf region (8 MB < 12.8 MB): m1 stays live (gemm1
  // writes it during the fused launch); histbuf has no other consumer
  // (h1p eliminated by the gather1+gemm2 fusion).
  unsigned* hist_src = (unsigned*)histbuf;                  // u8[NCHUNK*NBTH]
  unsigned* hist_dst = hist_src + (long)NCHUNK * NBTH / 4;  // u8[NCHUNK*NBTH]

  const int nb_nodes = (N_NODES + 255) / 256;  // 196

  // ---- W transposes (W1T consumed by the NEXT dispatch — stream-ordered)
  wtrans<<<160, 256, 0, stream>>>(W1, W2, W1T, W2T);
  // ---- fused: u8 degrees histogram + gemm1
  hist_gemm_kernel<<<HBLKH + ROWBLK, 256, 0, stream>>>(
      src, dst, hist_src, hist_dst, W1T, x, m1);
  reduce_kernel<<<nb_nodes, 256, 0, stream>>>(hist_src, hist_dst, deg_in,
                                              norm_src, norm_dst, partial);
  scan3<<<nb_nodes, 256, 0, stream>>>(deg_in, partial, rowptr);
  fill_csr<<<FBLK, 256, 0, stream>>>(src, dst, rowptr, hist_dst, col);

  // ---- layers 1+2a fused: gather1 (per-edge ns) + rows@W2T -> m2
  gather_gemm2_kernel<<<N_NODES / 16, 256, 0, stream>>>(
      m1, rowptr, col, norm_dst, norm_src, b1, W2T, m2);

  // ---- layer 2b: final aggregation
  gather2_kernel<<<(N_NODES + 3) / 4, 256, 0, stream>>>(m2, rowptr, col,
                                                        norm_dst, b2, out);
}

// Round 16
// 212.323 us; speedup vs baseline: 1.0163x; 1.0163x over previous
//
#include <hip/hip_runtime.h>

#define N_NODES 50000
#define N_EDGES 800000
#define IN_FEATS 256
#define HIDDEN 128
#define OUT_FEATS 64

// R27: REVERT to R25 (measured best, 214.4us). R26's deep-batch fast path
// regressed (gg2 43->48us): it rounds every node to 32 edge-slots (mean
// deg 16) -> ~2x dynamic loads+fmas (masked slots still issue), occupancy
// 58->40%. With beyond-L2 traffic pinned at the 8-XCD compulsory floor
// (~110MB) across R22-R26 and service ~2.6 TB/s invariant to dependency
// structure, the gather is at its random-row service floor; R25's minimal
// form is the optimum of this family.
#define NCHUNK 64            // edge chunks (= privatized copies)
#define EPC 12500            // edges per chunk
#define NBH 16384            // hist bins per range (u8)
#define NRH 4                // ceil(50000/16384)
#define NBTH (NRH * NBH)     // 65536 padded bins per copy (u8 each)
#define HBLKH (NRH * NCHUNK) // 256 hist blocks
#define NBF 8192             // fill bins per range (int cur, 32 KB)
#define NRF 7                // ceil(50000/8192)
#define FBLK (NRF * NCHUNK)  // 448 fill blocks
#define ROWBLK ((N_NODES + 63) / 64)  // 782 gemm blocks

typedef _Float16 f16;
typedef _Float16 f16x8 __attribute__((ext_vector_type(8)));
typedef float f32x4 __attribute__((ext_vector_type(4)));

// ------------------------------------------------------------ W transpose
// W1T[n][k] = W1[k][n] (128x256 f16); W2T[n][k] = W2[k][n] (64x128 f16).
__global__ __launch_bounds__(256) void wtrans(const float* __restrict__ W1,
                                              const float* __restrict__ W2,
                                              f16* __restrict__ W1T,
                                              f16* __restrict__ W2T) {
  int i = blockIdx.x * 256 + threadIdx.x;
  if (i < 128 * 256) {
    int n = i >> 8, k = i & 255;
    W1T[i] = (f16)W1[k * 128 + n];
  } else {
    int j = i - 128 * 256;
    int n = j >> 7, k = j & 127;
    W2T[j] = (f16)W2[k * 64 + n];
  }
}

// ------------------------------------------- fused hist + gemm1 kernel
// Blocks [0,256): u8 LDS histogram of src/dst (zero global atomics).
// Blocks [256,1038): gemm1 m1 = f16(X)@W1 — 64-row x 128-col tile, x
// row-frags in VGPRs (read once), two 64-col halves via one 32 KB
// XOR-swizzled LDS B-tile staged from W1T by f16x8 copy (8 iters/half).
// m1 UNSCALED — norm_src applied per-edge in gather by linearity.
__global__ __launch_bounds__(256) void hist_gemm_kernel(
    const int* __restrict__ src, const int* __restrict__ dst,
    unsigned* __restrict__ hist_src, unsigned* __restrict__ hist_dst,
    const f16* __restrict__ W1T, const float* __restrict__ x,
    f16* __restrict__ m1) {
  // union: u8 hist counters (2 x 16 KB) / gemm B-tile 64x256 f16 swizzled
  __shared__ __align__(16) unsigned smem[8192];  // 32768 B exactly
  if (blockIdx.x < HBLKH) {
    unsigned* ls = smem;             // u8[NBH] packed, src bins
    unsigned* ld2 = smem + NBH / 4;  // u8[NBH] packed, dst bins
    const int r = blockIdx.x % NRH;
    const int c = blockIdx.x / NRH;
    const int lo = r * NBH;
    for (int i = threadIdx.x; i < NBH / 4; i += 256) {
      ls[i] = 0;
      ld2[i] = 0;
    }
    __syncthreads();
    const int4* s4 = (const int4*)(src + c * EPC);
    const int4* d4 = (const int4*)(dst + c * EPC);
    for (int i = threadIdx.x; i < EPC / 4; i += 256) {
      int4 s = s4[i];
      int4 d = d4[i];
      unsigned b;
      b = (unsigned)(s.x - lo); if (b < NBH) atomicAdd(&ls[b >> 2], 1u << ((b & 3) << 3));
      b = (unsigned)(s.y - lo); if (b < NBH) atomicAdd(&ls[b >> 2], 1u << ((b & 3) << 3));
      b = (unsigned)(s.z - lo); if (b < NBH) atomicAdd(&ls[b >> 2], 1u << ((b & 3) << 3));
      b = (unsigned)(s.w - lo); if (b < NBH) atomicAdd(&ls[b >> 2], 1u << ((b & 3) << 3));
      b = (unsigned)(d.x - lo); if (b < NBH) atomicAdd(&ld2[b >> 2], 1u << ((b & 3) << 3));
      b = (unsigned)(d.y - lo); if (b < NBH) atomicAdd(&ld2[b >> 2], 1u << ((b & 3) << 3));
      b = (unsigned)(d.z - lo); if (b < NBH) atomicAdd(&ld2[b >> 2], 1u << ((b & 3) << 3));
      b = (unsigned)(d.w - lo); if (b < NBH) atomicAdd(&ld2[b >> 2], 1u << ((b & 3) << 3));
    }
    __syncthreads();
    unsigned* hs = hist_src + ((long)c * NBTH + lo) / 4;
    unsigned* hd = hist_dst + ((long)c * NBTH + lo) / 4;
    for (int i = threadIdx.x; i < NBH / 4; i += 256) {
      hs[i] = ls[i];
      hd[i] = ld2[i];
    }
  } else {
    // ------- gemm1: two 64-col halves, one 32 KB swizzled Bs.
    // Swizzle (both sides, same involution): byte ^= (n&7)<<4, n = out col.
    char* BsBytes = (char*)smem;
    const int rb = blockIdx.x - HBLKH;
    const int wave = threadIdx.x >> 6;
    const int lane = threadIdx.x & 63;
    const int m = lane & 15;
    const int q = lane >> 4;
    const int row0 = rb * 64 + wave * 16;
    const int ra = min(row0 + m, N_NODES - 1);

    // load + convert this lane's x row fragments ONCE (8 x f16x8 = 32 VGPR)
    f16x8 a[8];
#pragma unroll
    for (int ki = 0; ki < 8; ++ki) {
      const float* p = x + (long)ra * IN_FEATS + ki * 32 + q * 8;
      float4 u0 = *(const float4*)p;
      float4 u1 = *(const float4*)(p + 4);
      a[ki][0] = (f16)u0.x; a[ki][1] = (f16)u0.y;
      a[ki][2] = (f16)u0.z; a[ki][3] = (f16)u0.w;
      a[ki][4] = (f16)u1.x; a[ki][5] = (f16)u1.y;
      a[ki][6] = (f16)u1.z; a[ki][7] = (f16)u1.w;
    }

    for (int h = 0; h < 2; ++h) {
      const int col0 = h * 64;
      // stage Bs[n][0..255] = W1T[col0+n][0..255] as 16-B chunks; global
      // side fully coalesced, swizzled 16-B LDS writes bank-uniform.
#pragma unroll
      for (int idx = threadIdx.x; idx < 64 * 32; idx += 256) {
        int n = idx >> 5;
        int kq = idx & 31;
        f16x8 v = *(const f16x8*)(W1T + (col0 + n) * IN_FEATS + kq * 8);
        unsigned bo = (unsigned)(n * 512 + kq * 16);
        bo ^= (unsigned)((n & 7) << 4);
        *(f16x8*)(BsBytes + bo) = v;
      }
      __syncthreads();

      f32x4 acc[4];
#pragma unroll
      for (int t = 0; t < 4; ++t) acc[t] = (f32x4){0.f, 0.f, 0.f, 0.f};

#pragma unroll
      for (int ki = 0; ki < 8; ++ki) {
        const int kb2 = (ki * 32 + q * 8) * 2;  // byte offset in row
#pragma unroll
        for (int t = 0; t < 4; ++t) {
          int nrow = t * 16 + m;
          unsigned bo = (unsigned)(nrow * 512 + kb2);
          bo ^= (unsigned)((nrow & 7) << 4);
          f16x8 bfr = *(const f16x8*)(BsBytes + bo);
          acc[t] = __builtin_amdgcn_mfma_f32_16x16x32_f16(a[ki], bfr, acc[t], 0, 0, 0);
        }
      }
      __syncthreads();  // all reads of Bs done before next half's restage

#pragma unroll
      for (int rr = 0; rr < 4; ++rr) {
        int row = row0 + q * 4 + rr;
        if (row < N_NODES) {
#pragma unroll
          for (int t = 0; t < 4; ++t)
            m1[(long)row * HIDDEN + col0 + t * 16 + m] = (f16)acc[t][rr];
        }
      }
    }
  }
}

// sum copies -> norms; hist_dst -> exclusive prefix over copies (u8; max
// in-degree ~50 << 256); emits per-block degree sums (folded scan1).
__global__ __launch_bounds__(256) void reduce_kernel(
    const unsigned* __restrict__ hist_src, unsigned* __restrict__ hist_dst,
    int* __restrict__ deg_in, float* __restrict__ norm_src,
    float* __restrict__ norm_dst, int* __restrict__ partial) {
  const unsigned char* hs = (const unsigned char*)hist_src;
  unsigned char* hd = (unsigned char*)hist_dst;
  int n = blockIdx.x * 256 + threadIdx.x;
  int run = 0;
  if (n < N_NODES) {
    int so = 0;
#pragma unroll 8
    for (int c = 0; c < NCHUNK; ++c) so += hs[(long)c * NBTH + n];
    norm_src[n] = rsqrtf((float)max(so, 1));
#pragma unroll 8
    for (int c = 0; c < NCHUNK; ++c) {
      int t = hd[(long)c * NBTH + n];
      hd[(long)c * NBTH + n] = (unsigned char)run;
      run += t;
    }
    deg_in[n] = run;
    norm_dst[n] = rsqrtf((float)max(run, 1));
  }
  __shared__ int sd[256];
  sd[threadIdx.x] = run;
  __syncthreads();
  for (int s = 128; s > 0; s >>= 1) {
    if (threadIdx.x < s) sd[threadIdx.x] += sd[threadIdx.x + s];
    __syncthreads();
  }
  if (threadIdx.x == 0) partial[blockIdx.x] = sd[0];
}

// ------------------------------------------------- scan (scan2 folded in)
__global__ __launch_bounds__(256) void scan3(const int* __restrict__ deg,
                                             const int* __restrict__ partial,
                                             int* __restrict__ rowptr) {
  __shared__ int sd[256];
  __shared__ int sp[256];
  const int w = blockIdx.x;
  int pv = (threadIdx.x < 196) ? partial[threadIdx.x] : 0;
  sp[threadIdx.x] = pv;
  __syncthreads();
  for (int off = 1; off < 256; off <<= 1) {
    int t = sp[threadIdx.x] +
            ((threadIdx.x >= off) ? sp[threadIdx.x - off] : 0);
    __syncthreads();
    sp[threadIdx.x] = t;
    __syncthreads();
  }
  const int base = (w == 0) ? 0 : sp[w - 1];
  int i = w * 256 + threadIdx.x;
  int v = (i < N_NODES) ? deg[i] : 0;
  sd[threadIdx.x] = v;
  __syncthreads();
  for (int off = 1; off < 256; off <<= 1) {
    int t = sd[threadIdx.x] +
            ((threadIdx.x >= off) ? sd[threadIdx.x - off] : 0);
    __syncthreads();
    sd[threadIdx.x] = t;
    __syncthreads();
  }
  if (i < N_NODES) rowptr[i] = base + sd[threadIdx.x] - v;
  if (w == 0 && threadIdx.x == 0) rowptr[N_NODES] = N_EDGES;
}

// ------------------------------------------------------------- CSR fill
__global__ __launch_bounds__(256) void fill_csr(
    const int* __restrict__ src, const int* __restrict__ dst,
    const int* __restrict__ rowptr, const unsigned* __restrict__ pref32,
    int* __restrict__ col) {
  __shared__ int cur[NBF];  // 32 KB
  const unsigned char* pref = (const unsigned char*)pref32;
  const int r = blockIdx.x % NRF;
  const int c = blockIdx.x / NRF;
  const int lo = r * NBF;
  for (int i = threadIdx.x; i < NBF; i += 256) {
    int n = lo + i;
    cur[i] = (n < N_NODES) ? rowptr[n] + pref[(long)c * NBTH + n] : 0;
  }
  __syncthreads();
  const int4* s4 = (const int4*)(src + c * EPC);
  const int4* d4 = (const int4*)(dst + c * EPC);
  for (int i = threadIdx.x; i < EPC / 4; i += 256) {
    int4 s = s4[i];
    int4 d = d4[i];
    unsigned b;
    b = (unsigned)(d.x - lo);
    if (b < NBF) col[atomicAdd(&cur[b], 1)] = s.x;
    b = (unsigned)(d.y - lo);
    if (b < NBF) col[atomicAdd(&cur[b], 1)] = s.y;
    b = (unsigned)(d.z - lo);
    if (b < NBF) col[atomicAdd(&cur[b], 1)] = s.z;
    b = (unsigned)(d.w - lo);
    if (b < NBF) col[atomicAdd(&cur[b], 1)] = s.w;
  }
}

// ------------------------------------- fused gather1 + gemm2 (layer 1+2a)
// Block = 16 dst nodes (4 waves x 4 sequential). Uniform-shuffle edge
// loop: beg/end wave-uniform (wave = one node); rb loop bound uniform;
// r0/r1 < 64 always; out-of-range edges -> masked preload cns=0 -> exact
// zero contribution. Rows parked in padded LDS; one sync; each wave does
// one 16x16 tile of rows@W2T (4 MFMAs) straight to m2. 50000 = 3125*16.
__global__ __launch_bounds__(256) void gather_gemm2_kernel(
    const f16* __restrict__ M, const int* __restrict__ rowptr,
    const int* __restrict__ col, const float* __restrict__ nd,
    const float* __restrict__ ns, const float* __restrict__ b,
    const f16* __restrict__ W2T, f16* __restrict__ m2) {
  constexpr int LPR = 16;       // 128 f16 = 256 B row / 16 B per lane
  constexpr int EPW = 64 / LPR; // 4 edges in parallel
  constexpr int RS = 136;       // LDS row stride (f16): 272 B, 16-B aligned
  __shared__ __align__(16) f16 rows[16 * RS];  // 4352 B
  const int wave = threadIdx.x >> 6;
  const int lane = threadIdx.x & 63;
  const int eg = lane / LPR;
  const int t = lane % LPR;
  const int base = blockIdx.x * 16;

  for (int s = 0; s < 4; ++s) {
    const int n = base + wave * 4 + s;
    const int beg = rowptr[n];
    const int end = rowptr[n + 1];
    const int d64 = min(end - beg, 64);  // wave-uniform

    // batch preload: lane l holds col/ns of edge beg+l (masked -> 0)
    int e = beg + lane;
    int cidx = (e < end) ? col[e] : 0;
    float cns = (e < end) ? ns[cidx] : 0.f;

    float acc[8];
#pragma unroll
    for (int j = 0; j < 8; ++j) acc[j] = 0.f;

    // wave-uniform trip count; all lanes execute every __shfl (all
    // source lanes active). rb <= 56, r1 <= 56+3+4 = 63 < 64.
    for (int rb2 = 0; rb2 < d64; rb2 += 2 * EPW) {
      int r0 = rb2 + eg;
      int r1 = rb2 + eg + EPW;
      int s0 = __shfl(cidx, r0, 64);
      float n0 = __shfl(cns, r0, 64);
      int s1 = __shfl(cidx, r1, 64);
      float n1 = __shfl(cns, r1, 64);
      f16x8 v0 = *(const f16x8*)(M + (long)s0 * HIDDEN + t * 8);
      f16x8 v1 = *(const f16x8*)(M + (long)s1 * HIDDEN + t * 8);
#pragma unroll
      for (int j = 0; j < 8; ++j)
        acc[j] += n0 * (float)v0[j] + n1 * (float)v1[j];
    }
    // residual comb (deg > 64; essentially never taken, exact fallback)
    for (int i2 = beg + 64 + eg; i2 < end; i2 += EPW) {
      int s0 = col[i2];
      float n0 = ns[s0];
      f16x8 v0 = *(const f16x8*)(M + (long)s0 * HIDDEN + t * 8);
#pragma unroll
      for (int j = 0; j < 8; ++j) acc[j] += n0 * (float)v0[j];
    }

#pragma unroll
    for (int mm = LPR; mm < 64; mm <<= 1)
#pragma unroll
      for (int j = 0; j < 8; ++j) acc[j] += __shfl_xor(acc[j], mm, 64);

    if (eg == 0) {
      float sc = nd[n];
      float sn = ns[n];
      float4 bb0 = *(const float4*)(b + t * 8);
      float4 bb1 = *(const float4*)(b + t * 8 + 4);
      f16x8 o;
      o[0] = (f16)(fmaxf(acc[0] * sc + bb0.x, 0.f) * sn);
      o[1] = (f16)(fmaxf(acc[1] * sc + bb0.y, 0.f) * sn);
      o[2] = (f16)(fmaxf(acc[2] * sc + bb0.z, 0.f) * sn);
      o[3] = (f16)(fmaxf(acc[3] * sc + bb0.w, 0.f) * sn);
      o[4] = (f16)(fmaxf(acc[4] * sc + bb1.x, 0.f) * sn);
      o[5] = (f16)(fmaxf(acc[5] * sc + bb1.y, 0.f) * sn);
      o[6] = (f16)(fmaxf(acc[6] * sc + bb1.z, 0.f) * sn);
      o[7] = (f16)(fmaxf(acc[7] * sc + bb1.w, 0.f) * sn);
      *(f16x8*)(rows + (wave * 4 + s) * RS + t * 8) = o;
    }
  }
  __syncthreads();

  // GEMM tail: wave computes output cols [wave*16, wave*16+16) for the
  // block's 16 rows. K = HIDDEN = 128 -> 4 MFMA steps.
  const int m = lane & 15;
  const int q = lane >> 4;
  f32x4 acc2 = (f32x4){0.f, 0.f, 0.f, 0.f};
#pragma unroll
  for (int ki = 0; ki < 4; ++ki) {
    f16x8 a = *(const f16x8*)(rows + m * RS + ki * 32 + q * 8);
    f16x8 bf =
        *(const f16x8*)(W2T + (wave * 16 + m) * HIDDEN + ki * 32 + q * 8);
    acc2 = __builtin_amdgcn_mfma_f32_16x16x32_f16(a, bf, acc2, 0, 0, 0);
  }
#pragma unroll
  for (int r = 0; r < 4; ++r) {
    int row = base + q * 4 + r;
    m2[(long)row * OUT_FEATS + wave * 16 + m] = (f16)acc2[r];
  }
}

// ------------------------------------------------------------- gather2
// Uniform-shuffle scheme (LPR=8, EPW=8); unweighted sum -> explicit w in
// {0,1} zeroes out-of-range edges (fma(1,v,acc) == acc+v bit-exact).
__global__ __launch_bounds__(256) void gather2_kernel(
    const f16* __restrict__ M, const int* __restrict__ rowptr,
    const int* __restrict__ col, const float* __restrict__ nd,
    const float* __restrict__ b, float* __restrict__ out) {
  constexpr int LPR = 8;        // 64 f16 = 128 B row / 16 B per lane
  constexpr int EPW = 64 / LPR; // 8 edges in parallel
  const int wave = threadIdx.x >> 6;
  const int lane = threadIdx.x & 63;
  const int eg = lane / LPR;
  const int t = lane % LPR;
  const int n = blockIdx.x * 4 + wave;
  if (n >= N_NODES) return;
  const int beg = rowptr[n];
  const int end = rowptr[n + 1];
  const int d64 = min(end - beg, 64);  // wave-uniform

  // batch preload: lane l holds col/weight of edge beg+l (masked -> 0)
  int e = beg + lane;
  int cidx = (e < end) ? col[e] : 0;
  float cw = (e < end) ? 1.f : 0.f;

  float acc[8];
#pragma unroll
  for (int j = 0; j < 8; ++j) acc[j] = 0.f;

  // wave-uniform trip count; rb <= 48, r1 <= 48+7+8 = 63 < 64.
  for (int rb2 = 0; rb2 < d64; rb2 += 2 * EPW) {
    int r0 = rb2 + eg;
    int r1 = rb2 + eg + EPW;
    int s0 = __shfl(cidx, r0, 64);
    float w0 = __shfl(cw, r0, 64);
    int s1 = __shfl(cidx, r1, 64);
    float w1 = __shfl(cw, r1, 64);
    f16x8 v0 = *(const f16x8*)(M + (long)s0 * OUT_FEATS + t * 8);
    f16x8 v1 = *(const f16x8*)(M + (long)s1 * OUT_FEATS + t * 8);
#pragma unroll
    for (int j = 0; j < 8; ++j)
      acc[j] += w0 * (float)v0[j] + w1 * (float)v1[j];
  }
  // residual comb (deg > 64; essentially never taken, exact fallback)
  for (int i2 = beg + 64 + eg; i2 < end; i2 += EPW) {
    int s0 = col[i2];
    f16x8 v0 = *(const f16x8*)(M + (long)s0 * OUT_FEATS + t * 8);
#pragma unroll
    for (int j = 0; j < 8; ++j) acc[j] += (float)v0[j];
  }

#pragma unroll
  for (int m2v = LPR; m2v < 64; m2v <<= 1)
#pragma unroll
    for (int j = 0; j < 8; ++j) acc[j] += __shfl_xor(acc[j], m2v, 64);

  if (eg == 0) {
    float s = nd[n];
    float4 bb0 = *(const float4*)(b + t * 8);
    float4 bb1 = *(const float4*)(b + t * 8 + 4);
    float4 o0, o1;
    o0.x = acc[0] * s + bb0.x;
    o0.y = acc[1] * s + bb0.y;
    o0.z = acc[2] * s + bb0.z;
    o0.w = acc[3] * s + bb0.w;
    o1.x = acc[4] * s + bb1.x;
    o1.y = acc[5] * s + bb1.y;
    o1.z = acc[6] * s + bb1.z;
    o1.w = acc[7] * s + bb1.w;
    *(float4*)(out + (long)n * OUT_FEATS + t * 8) = o0;
    *(float4*)(out + (long)n * OUT_FEATS + t * 8 + 4) = o1;
  }
}

extern "C" void kernel_launch(void* const* d_in, const int* in_sizes, int n_in,
                              void* d_out, int out_size, void* d_ws,
                              size_t ws_size, hipStream_t stream) {
  const float* x = (const float*)d_in[0];
  const int* src = (const int*)d_in[1];
  const int* dst = (const int*)d_in[2];
  const float* W1 = (const float*)d_in[3];
  const float* b1 = (const float*)d_in[4];
  const float* W2 = (const float*)d_in[5];
  const float* b2 = (const float*)d_in[6];
  float* out = (float*)d_out;

  // ---- workspace layout
  int* wi = (int*)d_ws;
  int* partial = wi;            // [256]
  int* rowptr = wi + 256;       // [50001] (pad to 50004)
  int* deg_in = wi + 50260;     // [50000]
  int* col = wi + 100260;       // [800000] -> ends at int 900260
  float* wf = (float*)d_ws + 900260;
  float* norm_src = wf;         // [50000]
  float* norm_dst = wf + 50000; // [50000]
  f16* fh = (f16*)(wf + 100000);
  f16* W1T = fh;                          // [128*256]
  f16* W2T = fh + 128 * 256;              // [64*128]
  f16* m1 = W2T + 64 * 128;               // [50048*128]
  f16* histbuf = m1 + (long)50048 * 128;  // [50048*128] (hist tables only)
  f16* m2 = histbuf + (long)50048 * 128;  // [50048*64]

  // hist overlay on histbuf region (8 MB < 12.8 MB): m1 stays live (gemm1
  // writes it during the fused launch); histbuf has no other consumer
  // (h1p eliminated by the gather1+gemm2 fusion).
  unsigned* hist_src = (unsigned*)histbuf;                  // u8[NCHUNK*NBTH]
  unsigned* hist_dst = hist_src + (long)NCHUNK * NBTH / 4;  // u8[NCHUNK*NBTH]

  const int nb_nodes = (N_NODES + 255) / 256;  // 196

  // ---- W transposes (W1T consumed by the NEXT dispatch — stream-ordered)
  wtrans<<<160, 256, 0, stream>>>(W1, W2, W1T, W2T);
  // ---- fused: u8 degrees histogram + gemm1
  hist_gemm_kernel<<<HBLKH + ROWBLK, 256, 0, stream>>>(
      src, dst, hist_src, hist_dst, W1T, x, m1);
  reduce_kernel<<<nb_nodes, 256, 0, stream>>>(hist_src, hist_dst, deg_in,
                                              norm_src, norm_dst, partial);
  scan3<<<nb_nodes, 256, 0, stream>>>(deg_in, partial, rowptr);
  fill_csr<<<FBLK, 256, 0, stream>>>(src, dst, rowptr, hist_dst, col);

  // ---- layers 1+2a fused: gather1 (per-edge ns) + rows@W2T -> m2
  gather_gemm2_kernel<<<N_NODES / 16, 256, 0, stream>>>(
      m1, rowptr, col, norm_dst, norm_src, b1, W2T, m2);

  // ---- layer 2b: final aggregation
  gather2_kernel<<<(N_NODES + 3) / 4, 256, 0, stream>>>(m2, rowptr, col,
                                                        norm_dst, b2, out);
}